// Round 1
// baseline (813.551 us; speedup 1.0000x reference)
//
#include <hip/hip_runtime.h>
#include <math.h>

#define NN 1024
#define F 64
#define K 16

// -------------------- Top-K (17 smallest per row of D) --------------------
__global__ __launch_bounds__(256) void topk_kernel(const float* __restrict__ D,
                                                   int* __restrict__ selfIdx,
                                                   int* __restrict__ nbrIdx) {
    int row  = blockIdx.x * 4 + (threadIdx.x >> 6);   // 4096 rows total
    int lane = threadIdx.x & 63;
    const float* Drow = D + (size_t)row * NN;

    float v[16];
#pragma unroll
    for (int j = 0; j < 16; ++j) v[j] = Drow[j * 64 + lane];

    for (int t = 0; t < K + 1; ++t) {
        // local argmin over this lane's 16 cached values (lowest j wins ties)
        float bv = v[0]; int bj = 0;
#pragma unroll
        for (int j = 1; j < 16; ++j)
            if (v[j] < bv) { bv = v[j]; bj = j; }
        int bidx = bj * 64 + lane;
        // wave argmin, tie-break on lower index (matches jax top_k stability)
#pragma unroll
        for (int off = 32; off > 0; off >>= 1) {
            float ov = __shfl_xor(bv, off);
            int   oi = __shfl_xor(bidx, off);
            if (ov < bv || (ov == bv && oi < bidx)) { bv = ov; bidx = oi; }
        }
        if (lane == 0) {
            if (t == 0) selfIdx[row] = bidx;
            else        nbrIdx[row * K + (t - 1)] = bidx;
        }
        if ((bidx & 63) == lane) v[bidx >> 6] = INFINITY;
    }
}

// -------------------- Per-node fused edge compute --------------------
// One wave per node; lane = feature index (0..63). All math f32, fixed order.
__global__ __launch_bounds__(256) void node_kernel(
    const float* __restrict__ h,
    const float* __restrict__ W0, const float* __restrict__ b0,
    const float* __restrict__ W1, const float* __restrict__ b1,
    const float* __restrict__ W2, const float* __restrict__ b2,
    const float* __restrict__ Wl, const float* __restrict__ bl,
    const int* __restrict__ selfIdx, const int* __restrict__ nbrIdx,
    float* __restrict__ out) {

    __shared__ float s_lraw[4][64];
    __shared__ float s_x1[4][64];
    __shared__ float s_lab[4][64];
    __shared__ float s_U[4][256];
    __shared__ float s_xr[4][16];
    __shared__ float s_v[4][256];

    const int w    = threadIdx.x >> 6;
    const int lane = threadIdx.x & 63;
    const int bn   = blockIdx.x * 4 + w;      // 4096 nodes
    const int b    = bn >> 10;
    const float* hb = h + ((size_t)b << 10) * F;

    const int self = selfIdx[bn];
    const float x2 = hb[self * F + lane];
    const int r = lane & 15;                  // rank index (4 redundant groups)
    float acc = 0.f;
    const int shifts[4] = {0, 32, 48, 0};     // (ss+1)*16 for ss=1..3, mod 64

    for (int k = 0; k < K; ++k) {
        int nb = nbrIdx[bn * K + k];
        float x1 = hb[nb * F + lane];
        float lr = x1 - x2;

        float d = lr * lr;
#pragma unroll
        for (int off = 32; off > 0; off >>= 1) d += __shfl_xor(d, off);

        s_lraw[w][lane] = lr;
        s_x1[w][lane]   = x1;
        __syncthreads();

        // lab = leakyReLU(labels @ W0 + b0)
        float t = b0[lane];
#pragma unroll 8
        for (int j = 0; j < 64; ++j) t = fmaf(s_lraw[w][j], W0[j * 64 + lane], t);
        float lab = t > 0.f ? t : 0.02f * t;
        s_lab[w][lane] = lab;
        __syncthreads();

        // U_q[f] = sum_i W1[f, q*64+i] * x1[i]   (lane = f)
        float u0 = 0.f, u1 = 0.f, u2 = 0.f, u3 = 0.f;
        const float* w1row = W1 + lane * 256;
#pragma unroll 8
        for (int i = 0; i < 64; ++i) {
            float xi = s_x1[w][i];
            u0 = fmaf(w1row[i],        xi, u0);
            u1 = fmaf(w1row[64  + i],  xi, u1);
            u2 = fmaf(w1row[128 + i],  xi, u2);
            u3 = fmaf(w1row[192 + i],  xi, u3);
        }
        s_U[w][lane]       = u0;
        s_U[w][64  + lane] = u1;
        s_U[w][128 + lane] = u2;
        s_U[w][192 + lane] = u3;

        // thetal[r] and b1·x1[r]  (computed redundantly by 4 lane-groups)
        float thl = bl[r];
        float b1x = 0.f;
#pragma unroll 8
        for (int f = 0; f < 64; ++f) {
            thl = fmaf(s_lab[w][f], Wl[f * 16 + r], thl);
            b1x = fmaf(b1[r * 64 + f], s_x1[w][f], b1x);
        }
        __syncthreads();

        // xr[r] = (lab_rolled(p) · U_q + b1x) * thetal ,  p=r>>2, q=r&3
        {
            int p = r >> 2, q = r & 3;
            int sh = shifts[p];
            float t1 = b1x;
#pragma unroll 8
            for (int g = 0; g < 64; ++g)
                t1 = fmaf(s_lab[w][(g - sh) & 63], s_U[w][q * 64 + g], t1);
            float xr = t1 * thl;
            if (lane < 16) s_xr[w][lane] = xr;
        }
        __syncthreads();

        // v_q[f] = sum_p lab[(f - s_p)&63] * xr[4p+q]   (lane = f)
        {
            float v0 = 0.f, v1 = 0.f, v2 = 0.f, v3 = 0.f;
#pragma unroll
            for (int p = 0; p < 4; ++p) {
                float lp = s_lab[w][(lane - shifts[p]) & 63];
                v0 = fmaf(lp, s_xr[w][p * 4 + 0], v0);
                v1 = fmaf(lp, s_xr[w][p * 4 + 1], v1);
                v2 = fmaf(lp, s_xr[w][p * 4 + 2], v2);
                v3 = fmaf(lp, s_xr[w][p * 4 + 3], v3);
            }
            s_v[w][lane]       = v0;
            s_v[w][64  + lane] = v1;
            s_v[w][128 + lane] = v2;
            s_v[w][192 + lane] = v3;
        }
        __syncthreads();

        // xo[o] = sum_{q,f} v_q[f] * W2[f, q*64+o] + sum_r b2[r,o]*xr[r]  (lane = o)
        float xo = 0.f;
#pragma unroll 8
        for (int g = 0; g < 64; ++g) {
            const float* w2g = W2 + g * 256 + lane;
            xo = fmaf(s_v[w][g],        w2g[0],   xo);
            xo = fmaf(s_v[w][64  + g],  w2g[64],  xo);
            xo = fmaf(s_v[w][128 + g],  w2g[128], xo);
            xo = fmaf(s_v[w][192 + g],  w2g[192], xo);
        }
#pragma unroll
        for (int rr = 0; rr < 16; ++rr)
            xo = fmaf(b2[rr * 64 + lane], s_xr[w][rr], xo);

        acc = fmaf(expf(-d * 0.1f), xo, acc);
        __syncthreads();   // protect all LDS buffers before next iteration's writes
    }

    out[(size_t)bn * F + lane] = acc;
}

extern "C" void kernel_launch(void* const* d_in, const int* in_sizes, int n_in,
                              void* d_out, int out_size, void* d_ws, size_t ws_size,
                              hipStream_t stream) {
    const float* h  = (const float*)d_in[0];
    const float* D  = (const float*)d_in[1];
    const float* W0 = (const float*)d_in[2];
    const float* b0 = (const float*)d_in[3];
    const float* W1 = (const float*)d_in[4];
    const float* b1 = (const float*)d_in[5];
    const float* W2 = (const float*)d_in[6];
    const float* b2 = (const float*)d_in[7];
    const float* Wl = (const float*)d_in[8];
    const float* bl = (const float*)d_in[9];
    float* out = (float*)d_out;

    int* selfIdx = (int*)d_ws;            // 4096 ints
    int* nbrIdx  = selfIdx + 4096;        // 65536 ints  (~280 KB total)

    topk_kernel<<<1024, 256, 0, stream>>>(D, selfIdx, nbrIdx);
    node_kernel<<<1024, 256, 0, stream>>>(h, W0, b0, W1, b1, W2, b2, Wl, bl,
                                          selfIdx, nbrIdx, out);
}

// Round 2
// 339.271 us; speedup vs baseline: 2.3979x; 2.3979x over previous
//
#include <hip/hip_runtime.h>
#include <math.h>

#define NN 1024
#define F 64
#define K 16

__device__ __forceinline__ float rlane(float v, int l) {
    return __uint_as_float(__builtin_amdgcn_readlane(__float_as_uint(v), l));
}
__device__ __forceinline__ float rfirst(float v) {
    return __uint_as_float(__builtin_amdgcn_readfirstlane(__float_as_uint(v)));
}
__device__ __forceinline__ float wsum(float v) {
#pragma unroll
    for (int m = 32; m > 0; m >>= 1) v += __shfl_xor(v, m);
    return v;
}

// -------------------- tiny weight transposes into workspace --------------------
// W1T[c][j] = W1[j][c]  (256x64),  b1T[f][r] = b1[r][f]  (64x16)
__global__ __launch_bounds__(256) void transpose_kernel(const float* __restrict__ W1,
                                                        const float* __restrict__ b1,
                                                        float* __restrict__ W1T,
                                                        float* __restrict__ b1T) {
    int idx = blockIdx.x * 256 + threadIdx.x;
    if (idx < 16384) {
        int c = idx >> 6, j = idx & 63;
        W1T[idx] = W1[j * 256 + c];
    } else if (idx < 16384 + 1024) {
        int i2 = idx - 16384;
        int f = i2 >> 4, r = i2 & 15;
        b1T[i2] = b1[r * 64 + f];
    }
}

// -------------------- Top-K (17 smallest per row of D) --------------------
__global__ __launch_bounds__(256) void topk_kernel(const float* __restrict__ D,
                                                   int* __restrict__ selfIdx,
                                                   int* __restrict__ nbrIdx) {
    int row  = blockIdx.x * 4 + (threadIdx.x >> 6);
    int lane = threadIdx.x & 63;
    const float* Drow = D + (size_t)row * NN;

    float v[16];
#pragma unroll
    for (int j = 0; j < 16; ++j) v[j] = Drow[j * 64 + lane];

    for (int t = 0; t < K + 1; ++t) {
        float bv = v[0]; int bj = 0;
#pragma unroll
        for (int j = 1; j < 16; ++j)
            if (v[j] < bv) { bv = v[j]; bj = j; }
        int bidx = bj * 64 + lane;
#pragma unroll
        for (int off = 32; off > 0; off >>= 1) {
            float ov = __shfl_xor(bv, off);
            int   oi = __shfl_xor(bidx, off);
            if (ov < bv || (ov == bv && oi < bidx)) { bv = ov; bidx = oi; }
        }
        if (lane == 0) {
            if (t == 0) selfIdx[row] = bidx;
            else        nbrIdx[row * K + (t - 1)] = bidx;
        }
        if ((bidx & 63) == lane) v[bidx >> 6] = INFINITY;
    }
}

// -------------------- main: one wave per node, register-GEMV, no LDS --------------------
__global__ __launch_bounds__(256, 1) void node_kernel(
    const float* __restrict__ h,
    const float* __restrict__ W0, const float* __restrict__ b0,
    const float* __restrict__ W1T, const float* __restrict__ b1T,
    const float* __restrict__ W2, const float* __restrict__ b2,
    const float* __restrict__ Wl, const float* __restrict__ bl,
    const int* __restrict__ selfIdx, const int* __restrict__ nbrIdx,
    float* __restrict__ out) {

    const int w    = threadIdx.x >> 6;
    const int lane = threadIdx.x & 63;
    const int bn   = blockIdx.x * 4 + w;          // 4096 nodes
    const int r16  = lane & 15;
    const float* hb = h + ((size_t)(bn >> 10) << 10) * F;

    // ---- gather self + 16 neighbors (lane = feature) ----
    const int self = selfIdx[bn];
    const float x2 = hb[self * F + lane];

    int nb[K];
#pragma unroll
    for (int e = 0; e < K; ++e) nb[e] = nbrIdx[bn * K + e];

    float x1[K], lr[K];
#pragma unroll
    for (int e = 0; e < K; ++e) {
        x1[e] = hb[nb[e] * F + lane];
        lr[e] = x1[e] - x2;
    }

    // ---- d and exp(-d/10) (uniform scalars) ----
    float expd[K];
#pragma unroll
    for (int e = 0; e < K; ++e) {
        float d = wsum(lr[e] * lr[e]);
        expd[e] = rfirst(__expf(-d * 0.1f));
    }

    // ---- phase 1: lab[e] = leakyReLU(lr[e] @ W0 + b0), lane = out-feature ----
    float lab[K];
    {
        const float bb0 = b0[lane];
#pragma unroll
        for (int e = 0; e < K; ++e) lab[e] = bb0;
#pragma unroll 1
        for (int jc = 0; jc < 8; ++jc) {
            float w0b[8];
#pragma unroll
            for (int u = 0; u < 8; ++u) w0b[u] = W0[(jc * 8 + u) * 64 + lane];
#pragma unroll
            for (int e = 0; e < K; ++e)
#pragma unroll
                for (int u = 0; u < 8; ++u)
                    lab[e] = fmaf(rlane(lr[e], jc * 8 + u), w0b[u], lab[e]);
        }
#pragma unroll
        for (int e = 0; e < K; ++e) {
            float t = lab[e];
            lab[e] = t > 0.f ? t : 0.02f * t;
        }
    }

    // ---- rotated copies: lab32[f] = lab[(f-32)&63], lab48[f] = lab[(f-48)&63] ----
    float lab32[K], lab48[K];
#pragma unroll
    for (int e = 0; e < K; ++e) {
        lab32[e] = __shfl_xor(lab[e], 32);
        lab48[e] = __shfl(lab[e], (lane + 16) & 63);
    }

    // ---- phase 2: thl[e] (lane=r), b1x[e] (lane=r) ----
    float thl[K], b1x[K];
    {
        const float blv = bl[r16];
#pragma unroll
        for (int e = 0; e < K; ++e) { thl[e] = blv; b1x[e] = 0.f; }
#pragma unroll 1
        for (int fc = 0; fc < 8; ++fc) {
            float wlb[8], b1b[8];
#pragma unroll
            for (int u = 0; u < 8; ++u) {
                wlb[u] = Wl [(fc * 8 + u) * 16 + r16];
                b1b[u] = b1T[(fc * 8 + u) * 16 + r16];
            }
#pragma unroll
            for (int e = 0; e < K; ++e)
#pragma unroll
                for (int u = 0; u < 8; ++u) {
                    thl[e] = fmaf(rlane(lab[e], fc * 8 + u), wlb[u], thl[e]);
                    b1x[e] = fmaf(rlane(x1[e],  fc * 8 + u), b1b[u], b1x[e]);
                }
        }
    }

    // ---- phases 3+4 fused, per q-block ----
    float xo[K];
#pragma unroll
    for (int e = 0; e < K; ++e) xo[e] = 0.f;

#pragma unroll 1
    for (int q = 0; q < 4; ++q) {
        // U_q[e][lane=j] = sum_i x1[e][i] * W1[j][q*64+i]
        float Ue[K];
#pragma unroll
        for (int e = 0; e < K; ++e) Ue[e] = 0.f;
#pragma unroll 1
        for (int ic = 0; ic < 8; ++ic) {
            float w1b[8];
#pragma unroll
            for (int u = 0; u < 8; ++u)
                w1b[u] = W1T[(q * 64 + ic * 8 + u) * 64 + lane];
#pragma unroll
            for (int e = 0; e < K; ++e)
#pragma unroll
                for (int u = 0; u < 8; ++u)
                    Ue[e] = fmaf(rlane(x1[e], ic * 8 + u), w1b[u], Ue[e]);
        }

        // weights for the output GEMV of this q-block
        float w2b[64];
#pragma unroll
        for (int f = 0; f < 64; ++f) w2b[f] = W2[f * 256 + q * 64 + lane];
        float b2b[4];
#pragma unroll
        for (int p = 0; p < 4; ++p) b2b[p] = b2[(p * 4 + q) * 64 + lane];

#pragma unroll
        for (int e = 0; e < K; ++e) {
            // three distinct dots (p=0 and p=3 share shift 0)
            float d0  = wsum(lab[e]   * Ue[e]);
            float d32 = wsum(lab32[e] * Ue[e]);
            float d48 = wsum(lab48[e] * Ue[e]);

            // xr values for r = q, 4+q, 8+q, 12+q  (all-lane-equal vgprs)
            float xr0 = (d0  + rlane(b1x[e], q))      * rlane(thl[e], q);
            float xr1 = (d32 + rlane(b1x[e], 4 + q))  * rlane(thl[e], 4 + q);
            float xr2 = (d48 + rlane(b1x[e], 8 + q))  * rlane(thl[e], 8 + q);
            float xr3 = (d0  + rlane(b1x[e], 12 + q)) * rlane(thl[e], 12 + q);

            // v_q[e][lane=f] = lab*(xr0+xr3) + lab32*xr1 + lab48*xr2
            float vq = lab[e] * (xr0 + xr3);
            vq = fmaf(lab32[e], xr1, vq);
            vq = fmaf(lab48[e], xr2, vq);

            // xo[e][lane=o] += sum_f vq[f] * W2[f][q*64+o]   (4 partial chains)
            float a0 = 0.f, a1 = 0.f, a2 = 0.f, a3 = 0.f;
#pragma unroll
            for (int f4 = 0; f4 < 16; ++f4) {
                a0 = fmaf(rlane(vq, 4 * f4 + 0), w2b[4 * f4 + 0], a0);
                a1 = fmaf(rlane(vq, 4 * f4 + 1), w2b[4 * f4 + 1], a1);
                a2 = fmaf(rlane(vq, 4 * f4 + 2), w2b[4 * f4 + 2], a2);
                a3 = fmaf(rlane(vq, 4 * f4 + 3), w2b[4 * f4 + 3], a3);
            }
            xo[e] += (a0 + a1) + (a2 + a3);

            // b2 contribution: xr_p * b2[(4p+q)][o]
            xo[e] = fmaf(xr0, b2b[0], xo[e]);
            xo[e] = fmaf(xr1, b2b[1], xo[e]);
            xo[e] = fmaf(xr2, b2b[2], xo[e]);
            xo[e] = fmaf(xr3, b2b[3], xo[e]);
        }
    }

    // ---- phase 5: weighted sum over edges ----
    float acc = 0.f;
#pragma unroll
    for (int e = 0; e < K; ++e) acc = fmaf(expd[e], xo[e], acc);

    out[(size_t)bn * F + lane] = acc;
}

extern "C" void kernel_launch(void* const* d_in, const int* in_sizes, int n_in,
                              void* d_out, int out_size, void* d_ws, size_t ws_size,
                              hipStream_t stream) {
    const float* h  = (const float*)d_in[0];
    const float* D  = (const float*)d_in[1];
    const float* W0 = (const float*)d_in[2];
    const float* b0 = (const float*)d_in[3];
    const float* W1 = (const float*)d_in[4];
    const float* b1 = (const float*)d_in[5];
    const float* W2 = (const float*)d_in[6];
    const float* b2 = (const float*)d_in[7];
    const float* Wl = (const float*)d_in[8];
    const float* bl = (const float*)d_in[9];
    float* out = (float*)d_out;

    int*   selfIdx = (int*)d_ws;              // 4096
    int*   nbrIdx  = selfIdx + 4096;          // 65536
    float* W1T     = (float*)(nbrIdx + 65536);// 16384 floats
    float* b1T     = W1T + 16384;             // 1024 floats

    transpose_kernel<<<68, 256, 0, stream>>>(W1, b1, W1T, b1T);
    topk_kernel<<<1024, 256, 0, stream>>>(D, selfIdx, nbrIdx);
    node_kernel<<<1024, 256, 0, stream>>>(h, W0, b0, W1T, b1T, W2, b2, Wl, bl,
                                          selfIdx, nbrIdx, out);
}